// Round 1
// baseline (1287.030 us; speedup 1.0000x reference)
//
#include <hip/hip_runtime.h>
#include <math.h>

__global__ __launch_bounds__(256) void k_count_deg(const int* __restrict__ dst,
                                                   float* __restrict__ deg, int E) {
    int e = blockIdx.x * 256 + threadIdx.x;
    if (e < E) atomicAdd(&deg[dst[e]], 1.0f);
}

__global__ __launch_bounds__(256) void k_dinv(float* __restrict__ deg, int n) {
    int i = blockIdx.x * 256 + threadIdx.x;
    if (i < n) deg[i] = rsqrtf(deg[i] + 1.0f);  // +1 = self-loop
}

// h1 = x @ W1  (8 -> 64), also acc1 = h1 * dinv^2 (self-loop term pre-seeded)
__global__ __launch_bounds__(256) void k_gemm1(const float* __restrict__ x, const float* __restrict__ W1,
                                               const float* __restrict__ dinv, float* __restrict__ h1,
                                               float* __restrict__ acc1, int n) {
    __shared__ float w[512];
    for (int i = threadIdx.x; i < 512; i += 256) w[i] = W1[i];
    __syncthreads();
    int t = blockIdx.x * 256 + threadIdx.x;
    int node = t >> 6, j = t & 63;
    if (node >= n) return;
    float s = 0.f;
#pragma unroll
    for (int k = 0; k < 8; ++k) s += x[node * 8 + k] * w[k * 64 + j];
    h1[t] = s;
    float dv = dinv[node];
    acc1[t] = s * dv * dv;
}

// edge aggregation, 64 features: lane j handles feature j of edge e
__global__ __launch_bounds__(256) void k_agg64(const int* __restrict__ src, const int* __restrict__ dst,
                                               const float* __restrict__ dinv, const float* __restrict__ h,
                                               float* __restrict__ acc, int E) {
    int t = blockIdx.x * 256 + threadIdx.x;
    int e = t >> 6, j = t & 63;
    if (e >= E) return;
    int s = src[e], d = dst[e];
    float wn = dinv[s] * dinv[d];
    atomicAdd(&acc[d * 64 + j], h[s * 64 + j] * wn);
}

__global__ __launch_bounds__(256) void k_agg32(const int* __restrict__ src, const int* __restrict__ dst,
                                               const float* __restrict__ dinv, const float* __restrict__ h,
                                               float* __restrict__ acc, int E) {
    int t = blockIdx.x * 256 + threadIdx.x;
    int e = t >> 5, j = t & 31;
    if (e >= E) return;
    int s = src[e], d = dst[e];
    float wn = dinv[s] * dinv[d];
    atomicAdd(&acc[d * 32 + j], h[s * 32 + j] * wn);
}

// in-place: a = elu(a + b[j]);  mask = F-1 (F power of two)
__global__ __launch_bounds__(256) void k_elu_bias(float* __restrict__ a, const float* __restrict__ b,
                                                  int total, int mask) {
    int t = blockIdx.x * 256 + threadIdx.x;
    if (t >= total) return;
    float v = a[t] + b[t & mask];
    a[t] = v > 0.f ? v : expm1f(v);
}

// h2 = g1 @ W2 (64 -> 32), acc2 = h2 * dinv^2.  8 nodes / block, LDS tiles.
__global__ __launch_bounds__(256) void k_gemm2(const float* __restrict__ g1, const float* __restrict__ W2,
                                               const float* __restrict__ dinv, float* __restrict__ h2,
                                               float* __restrict__ acc2, int n) {
    __shared__ float w[2048];
    __shared__ float xs[512];
    for (int i = threadIdx.x; i < 2048; i += 256) w[i] = W2[i];
    int nb = blockIdx.x * 8;
    for (int i = threadIdx.x; i < 512; i += 256) {
        int r = i >> 6, c = i & 63;
        int node = nb + r;
        xs[i] = (node < n) ? g1[(size_t)node * 64 + c] : 0.f;
    }
    __syncthreads();
    int node = nb + (threadIdx.x >> 5);
    int j = threadIdx.x & 31;
    if (node >= n) return;
    const float* xr = &xs[(threadIdx.x >> 5) << 6];
    float s = 0.f;
#pragma unroll
    for (int k = 0; k < 64; ++k) s += xr[k] * w[k * 32 + j];
    float dv = dinv[node];
    h2[node * 32 + j] = s;
    acc2[node * 32 + j] = s * dv * dv;
}

// conv1d(32->16,k=3,VALID) + relu + fc(16->22); one thread per output row
__global__ __launch_bounds__(256) void k_head(const float* __restrict__ g2, const float* __restrict__ cw,
                                              const float* __restrict__ cb, const float* __restrict__ fw,
                                              const float* __restrict__ fb, float* __restrict__ out,
                                              int nrows) {
    __shared__ float scw[1536], sfw[352], scb[16], sfb[22];
    for (int i = threadIdx.x; i < 1536; i += 256) scw[i] = cw[i];
    for (int i = threadIdx.x; i < 352; i += 256) sfw[i] = fw[i];
    if (threadIdx.x < 16) scb[threadIdx.x] = cb[threadIdx.x];
    if (threadIdx.x < 22) sfb[threadIdx.x] = fb[threadIdx.x];
    __syncthreads();
    int l = blockIdx.x * 256 + threadIdx.x;
    if (l >= nrows) return;
    float xv[96];
    const float4* g4 = reinterpret_cast<const float4*>(g2);
#pragma unroll
    for (int k = 0; k < 3; ++k)
#pragma unroll
        for (int q = 0; q < 8; ++q) {
            float4 v = g4[(size_t)(l + k) * 8 + q];
            xv[k * 32 + q * 4 + 0] = v.x;
            xv[k * 32 + q * 4 + 1] = v.y;
            xv[k * 32 + q * 4 + 2] = v.z;
            xv[k * 32 + q * 4 + 3] = v.w;
        }
    float y[16];
#pragma unroll
    for (int co = 0; co < 16; ++co) {
        float s = scb[co];
#pragma unroll
        for (int ci = 0; ci < 32; ++ci) {
#pragma unroll
            for (int k = 0; k < 3; ++k)
                s += xv[k * 32 + ci] * scw[co * 96 + ci * 3 + k];
        }
        y[co] = s > 0.f ? s : 0.f;
    }
#pragma unroll
    for (int t = 0; t < 22; ++t) {
        float s = sfb[t];
#pragma unroll
        for (int co = 0; co < 16; ++co) s += y[co] * sfw[co * 22 + t];
        out[(size_t)l * 22 + t] = s;
    }
}

extern "C" void kernel_launch(void* const* d_in, const int* in_sizes, int n_in,
                              void* d_out, int out_size, void* d_ws, size_t ws_size,
                              hipStream_t stream) {
    const float* x  = (const float*)d_in[0];
    const int*   ei = (const int*)d_in[1];   // int32 (JAX x64 disabled)
    const float* W1 = (const float*)d_in[2];
    const float* b1 = (const float*)d_in[3];
    const float* W2 = (const float*)d_in[4];
    const float* b2 = (const float*)d_in[5];
    const float* cw = (const float*)d_in[6];
    const float* cb = (const float*)d_in[7];
    const float* fw = (const float*)d_in[8];
    const float* fb = (const float*)d_in[9];
    float* out = (float*)d_out;

    int N = in_sizes[0] / 8;       // 100000
    int E = in_sizes[1] / 2;       // 3200000
    const int* src = ei;
    const int* dst = ei + E;

    float* ws = (float*)d_ws;
    size_t offA = ((size_t)N + 255) & ~(size_t)255;
    float* dinv = ws;                        // [N]
    float* A    = ws + offA;                 // [N*64]
    float* B    = A + (size_t)N * 64;        // [N*64]
    float* h1   = A;
    float* acc1 = B;                         // becomes g1 after elu
    float* h2   = A;                         // reuse (h1 dead)
    float* acc2 = A + (size_t)N * 32;        // becomes g2 after elu

    hipMemsetAsync(dinv, 0, (size_t)N * sizeof(float), stream);
    k_count_deg<<<(E + 255) / 256, 256, 0, stream>>>(dst, dinv, E);
    k_dinv<<<(N + 255) / 256, 256, 0, stream>>>(dinv, N);

    k_gemm1<<<(int)(((size_t)N * 64 + 255) / 256), 256, 0, stream>>>(x, W1, dinv, h1, acc1, N);
    k_agg64<<<(int)(((size_t)E * 64 + 255) / 256), 256, 0, stream>>>(src, dst, dinv, h1, acc1, E);
    k_elu_bias<<<(int)(((size_t)N * 64 + 255) / 256), 256, 0, stream>>>(acc1, b1, N * 64, 63);

    k_gemm2<<<(N + 7) / 8, 256, 0, stream>>>(acc1, W2, dinv, h2, acc2, N);
    k_agg32<<<(int)(((size_t)E * 32 + 255) / 256), 256, 0, stream>>>(src, dst, dinv, h2, acc2, E);
    k_elu_bias<<<(int)(((size_t)N * 32 + 255) / 256), 256, 0, stream>>>(acc2, b2, N * 32, 31);

    k_head<<<(N - 2 + 255) / 256, 256, 0, stream>>>(acc2, cw, cb, fw, fb, out, N - 2);
}

// Round 2
// 649.040 us; speedup vs baseline: 1.9830x; 1.9830x over previous
//
#include <hip/hip_runtime.h>
#include <math.h>

// ---------------- degree / dinv ----------------
__global__ __launch_bounds__(256) void k_count(const int* __restrict__ dst,
                                               int* __restrict__ cnt, int E) {
    int e = blockIdx.x * 256 + threadIdx.x;
    if (e < E) atomicAdd(&cnt[dst[e]], 1);
}

__global__ __launch_bounds__(256) void k_dinv(const int* __restrict__ cnt,
                                              float* __restrict__ dinv, int n) {
    int i = blockIdx.x * 256 + threadIdx.x;
    if (i < n) dinv[i] = rsqrtf((float)cnt[i] + 1.0f);  // +1 = self-loop
}

// ---------------- exclusive scan (3 kernels) ----------------
__global__ __launch_bounds__(256) void k_scan1(const int* __restrict__ cnt,
                                               int* __restrict__ rowstart,
                                               int* __restrict__ bsum, int n) {
    __shared__ int s[256];
    int i = blockIdx.x * 256 + threadIdx.x;
    int v = (i < n) ? cnt[i] : 0;
    s[threadIdx.x] = v;
    __syncthreads();
    for (int off = 1; off < 256; off <<= 1) {
        int t = (threadIdx.x >= off) ? s[threadIdx.x - off] : 0;
        __syncthreads();
        s[threadIdx.x] += t;
        __syncthreads();
    }
    if (i < n) rowstart[i] = s[threadIdx.x] - v;  // block-local exclusive
    if (threadIdx.x == 255) bsum[blockIdx.x] = s[255];
}

__global__ __launch_bounds__(512) void k_scan2(int* __restrict__ bsum, int nb) {
    __shared__ int s[512];
    int v = (threadIdx.x < nb) ? bsum[threadIdx.x] : 0;
    s[threadIdx.x] = v;
    __syncthreads();
    for (int off = 1; off < 512; off <<= 1) {
        int t = (threadIdx.x >= off) ? s[threadIdx.x - off] : 0;
        __syncthreads();
        s[threadIdx.x] += t;
        __syncthreads();
    }
    if (threadIdx.x < nb) bsum[threadIdx.x] = s[threadIdx.x] - v;  // exclusive
}

__global__ __launch_bounds__(256) void k_scan3(int* __restrict__ rowstart,
                                               const int* __restrict__ bsum, int n, int E) {
    int i = blockIdx.x * 256 + threadIdx.x;
    if (i < n) rowstart[i] += bsum[blockIdx.x];
    if (i == 0) rowstart[n] = E;
}

// ---------------- scatter into CSR ----------------
__global__ __launch_bounds__(256) void k_scatter(const int* __restrict__ src,
                                                 const int* __restrict__ dst,
                                                 const int* __restrict__ rowstart,
                                                 int* __restrict__ cur,
                                                 int* __restrict__ csr, int E) {
    int e = blockIdx.x * 256 + threadIdx.x;
    if (e >= E) return;
    int d = dst[e];
    int p = rowstart[d] + atomicAdd(&cur[d], 1);
    csr[p] = src[e];
}

// ---------------- h1 = x @ W1 (8 -> 64) ----------------
__global__ __launch_bounds__(256) void k_gemm1(const float* __restrict__ x, const float* __restrict__ W1,
                                               const float* __restrict__ dinv, float* __restrict__ h1,
                                               float* __restrict__ acc1, int n) {
    __shared__ float w[512];
    for (int i = threadIdx.x; i < 512; i += 256) w[i] = W1[i];
    __syncthreads();
    int t = blockIdx.x * 256 + threadIdx.x;
    int node = t >> 6, j = t & 63;
    if (node >= n) return;
    float s = 0.f;
#pragma unroll
    for (int k = 0; k < 8; ++k) s += x[node * 8 + k] * w[k * 64 + j];
    h1[t] = s;
    if (acc1) {  // fallback path: seed accumulator with self-loop term
        float dv = dinv[node];
        acc1[t] = s * dv * dv;
    }
}

// ---------------- CSR gather-aggregate, 64 feats, fused bias+ELU ----------------
__global__ __launch_bounds__(256) void k_aggr64(const int* __restrict__ rs, const int* __restrict__ csr,
                                                const float* __restrict__ dinv, const float* __restrict__ h,
                                                const float* __restrict__ bias, float* __restrict__ g, int n) {
    int wid = (blockIdx.x * 256 + threadIdx.x) >> 6;
    if (wid >= n) return;
    int j = threadIdx.x & 63;
    int start = rs[wid], end = rs[wid + 1];
    float a = 0.f;
    int i = start;
    for (; i + 4 <= end; i += 4) {
        int s0 = csr[i], s1 = csr[i + 1], s2 = csr[i + 2], s3 = csr[i + 3];
        float w0 = dinv[s0], w1 = dinv[s1], w2 = dinv[s2], w3 = dinv[s3];
        a += h[(size_t)s0 * 64 + j] * w0;
        a += h[(size_t)s1 * 64 + j] * w1;
        a += h[(size_t)s2 * 64 + j] * w2;
        a += h[(size_t)s3 * 64 + j] * w3;
    }
    for (; i < end; ++i) {
        int s = csr[i];
        a += h[(size_t)s * 64 + j] * dinv[s];
    }
    float dv = dinv[wid];
    float v = dv * (a + dv * h[(size_t)wid * 64 + j]) + bias[j];
    g[(size_t)wid * 64 + j] = v > 0.f ? v : expm1f(v);
}

// ---------------- CSR gather-aggregate, 32 feats (2 edges per wave-half) ----------------
__global__ __launch_bounds__(256) void k_aggr32(const int* __restrict__ rs, const int* __restrict__ csr,
                                                const float* __restrict__ dinv, const float* __restrict__ h,
                                                const float* __restrict__ bias, float* __restrict__ g, int n) {
    int wid = (blockIdx.x * 256 + threadIdx.x) >> 6;
    if (wid >= n) return;
    int j = threadIdx.x & 31;
    int half = (threadIdx.x >> 5) & 1;
    int start = rs[wid], end = rs[wid + 1];
    float a = 0.f;
    int i = start + half;
    for (; i + 2 < end; i += 4) {
        int s0 = csr[i], s1 = csr[i + 2];
        a += h[(size_t)s0 * 32 + j] * dinv[s0];
        a += h[(size_t)s1 * 32 + j] * dinv[s1];
    }
    for (; i < end; i += 2) {
        int s = csr[i];
        a += h[(size_t)s * 32 + j] * dinv[s];
    }
    a += __shfl_xor(a, 32);
    if (half == 0) {
        float dv = dinv[wid];
        float v = dv * (a + dv * h[(size_t)wid * 32 + j]) + bias[j];
        g[(size_t)wid * 32 + j] = v > 0.f ? v : expm1f(v);
    }
}

// ---------------- h2 = g1 @ W2 (64 -> 32) ----------------
__global__ __launch_bounds__(256) void k_gemm2(const float* __restrict__ g1, const float* __restrict__ W2,
                                               const float* __restrict__ dinv, float* __restrict__ h2,
                                               float* __restrict__ acc2, int n) {
    __shared__ float w[2048];
    __shared__ float xs[512];
    for (int i = threadIdx.x; i < 2048; i += 256) w[i] = W2[i];
    int nb = blockIdx.x * 8;
    for (int i = threadIdx.x; i < 512; i += 256) {
        int r = i >> 6, c = i & 63;
        int node = nb + r;
        xs[i] = (node < n) ? g1[(size_t)node * 64 + c] : 0.f;
    }
    __syncthreads();
    int node = nb + (threadIdx.x >> 5);
    int j = threadIdx.x & 31;
    if (node >= n) return;
    const float* xr = &xs[(threadIdx.x >> 5) << 6];
    float s = 0.f;
#pragma unroll
    for (int k = 0; k < 64; ++k) s += xr[k] * w[k * 32 + j];
    h2[(size_t)node * 32 + j] = s;
    if (acc2) {
        float dv = dinv[node];
        acc2[(size_t)node * 32 + j] = s * dv * dv;
    }
}

// ---------------- fallback atomic aggregation + elu ----------------
__global__ __launch_bounds__(256) void k_agg64_at(const int* __restrict__ src, const int* __restrict__ dst,
                                                  const float* __restrict__ dinv, const float* __restrict__ h,
                                                  float* __restrict__ acc, int E) {
    int t = blockIdx.x * 256 + threadIdx.x;
    int e = t >> 6, j = t & 63;
    if (e >= E) return;
    int s = src[e], d = dst[e];
    atomicAdd(&acc[(size_t)d * 64 + j], h[(size_t)s * 64 + j] * dinv[s] * dinv[d]);
}

__global__ __launch_bounds__(256) void k_agg32_at(const int* __restrict__ src, const int* __restrict__ dst,
                                                  const float* __restrict__ dinv, const float* __restrict__ h,
                                                  float* __restrict__ acc, int E) {
    int t = blockIdx.x * 256 + threadIdx.x;
    int e = t >> 5, j = t & 31;
    if (e >= E) return;
    int s = src[e], d = dst[e];
    atomicAdd(&acc[(size_t)d * 32 + j], h[(size_t)s * 32 + j] * dinv[s] * dinv[d]);
}

__global__ __launch_bounds__(256) void k_elu_bias(float* __restrict__ a, const float* __restrict__ b,
                                                  int total, int mask) {
    int t = blockIdx.x * 256 + threadIdx.x;
    if (t >= total) return;
    float v = a[t] + b[t & mask];
    a[t] = v > 0.f ? v : expm1f(v);
}

// ---------------- conv1d(32->16,k=3) + relu + fc(16->22) ----------------
__global__ __launch_bounds__(256) void k_head(const float* __restrict__ g2, const float* __restrict__ cw,
                                              const float* __restrict__ cb, const float* __restrict__ fw,
                                              const float* __restrict__ fb, float* __restrict__ out,
                                              int nrows) {
    __shared__ float scw[1536], sfw[352], scb[16], sfb[22];
    for (int i = threadIdx.x; i < 1536; i += 256) scw[i] = cw[i];
    for (int i = threadIdx.x; i < 352; i += 256) sfw[i] = fw[i];
    if (threadIdx.x < 16) scb[threadIdx.x] = cb[threadIdx.x];
    if (threadIdx.x < 22) sfb[threadIdx.x] = fb[threadIdx.x];
    __syncthreads();
    int l = blockIdx.x * 256 + threadIdx.x;
    if (l >= nrows) return;
    float xv[96];
    const float4* g4 = reinterpret_cast<const float4*>(g2);
#pragma unroll
    for (int k = 0; k < 3; ++k)
#pragma unroll
        for (int q = 0; q < 8; ++q) {
            float4 v = g4[(size_t)(l + k) * 8 + q];
            xv[k * 32 + q * 4 + 0] = v.x;
            xv[k * 32 + q * 4 + 1] = v.y;
            xv[k * 32 + q * 4 + 2] = v.z;
            xv[k * 32 + q * 4 + 3] = v.w;
        }
    float y[16];
#pragma unroll
    for (int co = 0; co < 16; ++co) {
        float s = scb[co];
#pragma unroll
        for (int ci = 0; ci < 32; ++ci) {
#pragma unroll
            for (int k = 0; k < 3; ++k)
                s += xv[k * 32 + ci] * scw[co * 96 + ci * 3 + k];
        }
        y[co] = s > 0.f ? s : 0.f;
    }
#pragma unroll
    for (int t = 0; t < 22; ++t) {
        float s = sfb[t];
#pragma unroll
        for (int co = 0; co < 16; ++co) s += y[co] * sfw[co * 22 + t];
        out[(size_t)l * 22 + t] = s;
    }
}

extern "C" void kernel_launch(void* const* d_in, const int* in_sizes, int n_in,
                              void* d_out, int out_size, void* d_ws, size_t ws_size,
                              hipStream_t stream) {
    const float* x  = (const float*)d_in[0];
    const int*   ei = (const int*)d_in[1];   // int32 (JAX x64 disabled)
    const float* W1 = (const float*)d_in[2];
    const float* b1 = (const float*)d_in[3];
    const float* W2 = (const float*)d_in[4];
    const float* b2 = (const float*)d_in[5];
    const float* cw = (const float*)d_in[6];
    const float* cb = (const float*)d_in[7];
    const float* fw = (const float*)d_in[8];
    const float* fb = (const float*)d_in[9];
    float* out = (float*)d_out;

    int N = in_sizes[0] / 8;       // 100000
    int E = in_sizes[1] / 2;       // 3200000
    const int* src = ei;
    const int* dst = ei + E;

    auto align256 = [](size_t v) { return (v + 255) & ~(size_t)255; };
    float* ws = (float*)d_ws;
    size_t o = 0;
    float* dinv = ws + o;           o += align256(N);
    int* cnt = (int*)(ws + o);      o += align256(N);
    int* rowstart = (int*)(ws + o); o += align256(N + 1);
    int* bsum = (int*)(ws + o);     o += 512;
    int* csr = (int*)(ws + o);      o += align256(E);
    float* A = ws + o;              o += (size_t)N * 64;   // h1, later h2
    float* B = ws + o;              o += (size_t)N * 64;   // g1, later g2
    size_t needed = o * sizeof(float);

    int nb = (N + 255) / 256;  // scan blocks (391)

    if (ws_size >= needed) {
        // ---- CSR gather path ----
        hipMemsetAsync(cnt, 0, (size_t)N * sizeof(int), stream);
        k_count<<<(E + 255) / 256, 256, 0, stream>>>(dst, cnt, E);
        k_dinv<<<nb, 256, 0, stream>>>(cnt, dinv, N);
        k_scan1<<<nb, 256, 0, stream>>>(cnt, rowstart, bsum, N);
        k_scan2<<<1, 512, 0, stream>>>(bsum, nb);
        k_scan3<<<nb, 256, 0, stream>>>(rowstart, bsum, N, E);
        hipMemsetAsync(cnt, 0, (size_t)N * sizeof(int), stream);
        k_scatter<<<(E + 255) / 256, 256, 0, stream>>>(src, dst, rowstart, cnt, csr, E);

        float* h1 = A;
        float* g1 = B;
        k_gemm1<<<(int)(((size_t)N * 64 + 255) / 256), 256, 0, stream>>>(x, W1, dinv, h1, nullptr, N);
        k_aggr64<<<(int)(((size_t)N * 64 + 255) / 256), 256, 0, stream>>>(rowstart, csr, dinv, h1, b1, g1, N);

        float* h2 = A;
        float* g2 = B;
        k_gemm2<<<(N + 7) / 8, 256, 0, stream>>>(g1, W2, dinv, h2, nullptr, N);
        k_aggr32<<<(int)(((size_t)N * 64 + 255) / 256), 256, 0, stream>>>(rowstart, csr, dinv, h2, b2, g2, N);

        k_head<<<(N - 2 + 255) / 256, 256, 0, stream>>>(g2, cw, cb, fw, fb, out, N - 2);
    } else {
        // ---- fallback: atomic scatter path (round-1 behavior) ----
        float* h1 = A;
        float* acc1 = B;
        hipMemsetAsync(cnt, 0, (size_t)N * sizeof(int), stream);
        k_count<<<(E + 255) / 256, 256, 0, stream>>>(dst, cnt, E);
        k_dinv<<<nb, 256, 0, stream>>>(cnt, dinv, N);

        k_gemm1<<<(int)(((size_t)N * 64 + 255) / 256), 256, 0, stream>>>(x, W1, dinv, h1, acc1, N);
        k_agg64_at<<<(int)(((size_t)E * 64 + 255) / 256), 256, 0, stream>>>(src, dst, dinv, h1, acc1, E);
        k_elu_bias<<<(int)(((size_t)N * 64 + 255) / 256), 256, 0, stream>>>(acc1, b1, N * 64, 63);

        float* h2 = A;
        float* acc2 = A + (size_t)N * 32;
        k_gemm2<<<(N + 7) / 8, 256, 0, stream>>>(acc1, W2, dinv, h2, acc2, N);
        k_agg32_at<<<(int)(((size_t)E * 32 + 255) / 256), 256, 0, stream>>>(src, dst, dinv, h2, acc2, E);
        k_elu_bias<<<(int)(((size_t)N * 32 + 255) / 256), 256, 0, stream>>>(acc2, b2, N * 32, 31);

        k_head<<<(N - 2 + 255) / 256, 256, 0, stream>>>(acc2, cw, cb, fw, fb, out, N - 2);
    }
}